// Round 10
// baseline (53.318 us; speedup 1.0000x reference)
//
#include <hip/hip_runtime.h>

#define Bc 8
#define Nc 360
#define Dc 128
#define NSLOT 132      // padded slots per side = 33 groups of 4
#define NG 33
#define NC2 264        // slots both sides (B-side first, then A-side)

typedef float f32x4 __attribute__((ext_vector_type(4)));

// ---------------- fillw: permutation + packed/permuted/0.5*w2-scaled W1 + b1p + rs zeroing ----
__global__ __launch_bounds__(256) void fillw_kernel(
    const float* __restrict__ W1, const float* __restrict__ W2, const float* __restrict__ b1,
    float* __restrict__ W1p, float* __restrict__ b1p, int* __restrict__ gsplit_g,
    float* __restrict__ rs)   // rs = rsA (rsB contiguous after it), 2*Bc*Nc floats
{
    __shared__ int pmap_s[NSLOT];
    const int t  = threadIdx.x;
    const int k4 = blockIdx.x;                        // 0..31

    if (t < 64) {                                     // exactly wave 0
        const int lane = t;
        pmap_s[lane] = -1; pmap_s[64 + lane] = -1;
        if (lane < 4) pmap_s[128 + lane] = -1;
        const bool p0 = W2[lane] >= 0.0f;
        const bool p1 = W2[64 + lane] >= 0.0f;
        const unsigned long long m0 = __ballot(p0);
        const unsigned long long m1 = __ballot(p1);
        const unsigned long long below = (lane == 0) ? 0ull : (~0ull >> (64 - lane));
        const int cnt = __popcll(m0) + __popcll(m1);
        const int gs  = (cnt + 3) >> 2;
        if (lane == 0 && k4 == 0) *gsplit_g = gs;
        const int pr0 = __popcll(m0 & below);
        const int pr1 = __popcll(m0) + __popcll(m1 & below);
        const int nr0 = __popcll(~m0 & below);
        const int nr1 = __popcll(~m0) + __popcll(~m1 & below);
        // same-wave LDS writes are program-ordered: clears above, ranked scatter below
        if (p0) pmap_s[pr0] = lane;      else pmap_s[gs * 4 + nr0] = lane;
        if (p1) pmap_s[pr1] = 64 + lane; else pmap_s[gs * 4 + nr1] = 64 + lane;
    }
    __syncthreads();

    for (int c = t; c < NC2; c += 256) {
        const int side = (c >= NSLOT);               // 0 = B (sender), 1 = A (receiver)
        const int cm   = side ? c - NSLOT : c;
        const int pd   = pmap_s[cm];
        f32x4 v = {0.f, 0.f, 0.f, 0.f};
        if (pd >= 0) {
            const float sc = 0.5f * W2[pd];
            const float* src = W1 + pd * (2 * Dc) + side * Dc + k4 * 4;
            v[0] = sc * src[0]; v[1] = sc * src[1]; v[2] = sc * src[2]; v[3] = sc * src[3];
        }
        *(f32x4*)(W1p + (k4 * NC2 + c) * 4) = v;
        if (k4 == 0)
            b1p[c] = (side && pd >= 0) ? 0.5f * W2[pd] * b1[pd] : 0.0f;
    }

    // zero row-sum accumulators: 32 blocks x 256 threads = 8192 >= 5760
    const int idx = k4 * 256 + t;
    if (idx < 2 * Bc * Nc) rs[idx] = 0.0f;
}

// ---------------- proj ----------------
// Avp[b*360+n][s] = A'-slot values; Btp[b][g][n][e] = B'-slot values; rs* = row sums (atomic).
// Wave: lane <-> slot column c (coalesced W1p loads); 8 rows via VMEM broadcast loads.
// The row-base offset is made divergent with an OPAQUE asm v_mov zero (mbcnt folded — r9 lesson),
// so the compiler must keep emb loads in the pipelined global_load/vmcnt path, not s_load drains.
__global__ __launch_bounds__(64) void proj_kernel(
    const float* __restrict__ emb, const float* __restrict__ W1p, const float* __restrict__ b1p,
    float* __restrict__ Avp, float* __restrict__ Btp,
    float* __restrict__ rsA, float* __restrict__ rsB)
{
    const int lane = threadIdx.x;
    const int r0   = blockIdx.x * 8;                 // 2880/8 = 360; 360%8==0 -> one batch per block
    const int cg   = blockIdx.y;                     // 0..4
    const int c    = cg * 64 + lane;                 // 0..319
    const int cc   = (c < NC2) ? c : (NC2 - 1);      // clamp for loads

    int dz;                                          // == 0, opaque to the compiler
    asm volatile("v_mov_b32 %0, 0" : "=v"(dz));

    float acc[8];
    const float binit = b1p[cc];
    #pragma unroll
    for (int r = 0; r < 8; ++r) acc[r] = binit;

    const float* wp = W1p + cc * 4;
    const float* ep = emb + (r0 + dz) * Dc;          // divergent base -> VMEM broadcast loads

    #pragma unroll 4
    for (int k4 = 0; k4 < 32; ++k4) {
        const f32x4 wv = *(const f32x4*)(wp + k4 * NC2 * 4);   // coalesced b128
        #pragma unroll
        for (int r = 0; r < 8; ++r) {
            const f32x4 ev = *(const f32x4*)(ep + r * Dc + k4 * 4);  // broadcast (1 line)
            acc[r] = fmaf(wv[0], ev[0], acc[r]);
            acc[r] = fmaf(wv[1], ev[1], acc[r]);
            acc[r] = fmaf(wv[2], ev[2], acc[r]);
            acc[r] = fmaf(wv[3], ev[3], acc[r]);
        }
    }

    const bool valid = (c < NC2);
    const int  side  = (c >= NSLOT);                 // per-lane
    const int  cm    = side ? c - NSLOT : c;
    const int  bidx  = r0 / Nc;                      // uniform
    const int  nb    = r0 - bidx * Nc;

    #pragma unroll
    for (int r = 0; r < 8; ++r) {
        const int n = nb + r;
        if (valid) {
            if (side) Avp[(bidx * Nc + n) * NSLOT + cm] = acc[r];                       // contiguous
            else      Btp[((bidx * NG + (cm >> 2)) * Nc + n) * 4 + (cm & 3)] = acc[r];  // 16B segs
        }
        float vA = (valid && side)  ? acc[r] : 0.0f;
        float vB = (valid && !side) ? acc[r] : 0.0f;
        #pragma unroll
        for (int m = 32; m >= 1; m >>= 1) { vA += __shfl_xor(vA, m); vB += __shfl_xor(vB, m); }
        if (lane == 0) {
            if (cg >= 2) atomicAdd(rsA + bidx * Nc + n, vA);
            if (cg <= 2) atomicAdd(rsB + bidx * Nc + n, vB);
        }
    }
}

// ---------------- edge ----------------
// out[b,i,j] = relu( b2 + rsA[i] + rsB[j] + sum_g sgn_g * sum_e |a[g,e] + b[j,g,e]| )
// Block = 4 waves; wave = 1 i-row x 192 j (3 per lane). Grid (90, 2, 8) = 1440 blocks.
// a-row in SGPRs (chunked preload, static indices); B per-lane coalesced b128 from Btp.
__global__ __launch_bounds__(256) void edge_kernel(
    const float* __restrict__ Avp, const float* __restrict__ Btp,
    const float* __restrict__ b2, const float* __restrict__ rsA,
    const float* __restrict__ rsB, const int* __restrict__ gsplit_p,
    float* __restrict__ out)
{
    const int t    = threadIdx.x;
    const int lane = t & 63;
    const int wid  = __builtin_amdgcn_readfirstlane(t >> 6);
    const int b    = blockIdx.z;
    const int i    = blockIdx.x * 4 + wid;           // uniform per wave
    const int j0   = blockIdx.y * 168;               // halves [0,192) and [168,360): overlap idempotent
    const int gsplit = *gsplit_p;                    // uniform

    const float* arow = Avp + (b * Nc + i) * NSLOT;  // uniform -> s_load
    const float* bp   = Btp + (b * NG * Nc + j0 + lane) * 4;   // per-lane; + g*Nc*4 per group

    float acc0 = 0.0f, acc1 = 0.0f, acc2 = 0.0f;

    #pragma unroll
    for (int ch = 0; ch < 3; ++ch) {
        float a_ch[44];
        #pragma unroll
        for (int s = 0; s < 44; ++s) a_ch[s] = arow[ch * 44 + s];   // uniform -> SGPRs
        #pragma unroll
        for (int g2 = 0; g2 < 11; ++g2) {
            const int g = ch * 11 + g2;
            const float sg = (g < gsplit) ? 1.0f : -1.0f;            // uniform select
            const f32x4 b0 = *(const f32x4*)(bp + (g * Nc +   0) * 4);
            const f32x4 b1v = *(const f32x4*)(bp + (g * Nc +  64) * 4);
            const f32x4 b2v = *(const f32x4*)(bp + (g * Nc + 128) * 4);
            #pragma unroll
            for (int e = 0; e < 4; ++e) {
                const float a = a_ch[g2 * 4 + e];
                acc0 = fmaf(sg, fabsf(a + b0[e]),  acc0);
                acc1 = fmaf(sg, fabsf(a + b1v[e]), acc1);
                acc2 = fmaf(sg, fabsf(a + b2v[e]), acc2);
            }
        }
    }

    const float base = b2[0] + rsA[b * Nc + i];
    float* orow = out + (b * Nc + i) * Nc;
    orow[j0 + lane      ] = fmaxf(base + rsB[b * Nc + j0 + lane      ] + acc0, 0.0f);
    orow[j0 + lane +  64] = fmaxf(base + rsB[b * Nc + j0 + lane +  64] + acc1, 0.0f);
    orow[j0 + lane + 128] = fmaxf(base + rsB[b * Nc + j0 + lane + 128] + acc2, 0.0f);
}

extern "C" void kernel_launch(void* const* d_in, const int* in_sizes, int n_in,
                              void* d_out, int out_size, void* d_ws, size_t ws_size,
                              hipStream_t stream) {
    const float* emb = (const float*)d_in[0];   // [B,N,D]
    const float* W1  = (const float*)d_in[1];   // [D, 2D]
    const float* b1  = (const float*)d_in[2];   // [D]
    const float* W2  = (const float*)d_in[3];   // [1, D]
    const float* b2  = (const float*)d_in[4];   // [1]
    float* out = (float*)d_out;                 // [B,N,N,1]

    float* W1p = (float*)d_ws;                  // [32][264][4]          = 33792
    float* b1p = W1p + 32 * NC2 * 4;            // [264]
    float* Avp = b1p + NC2;                     // [2880][132]           = 380160
    float* Btp = Avp + Bc * Nc * NSLOT;         // [8][33][360][4]       = 380160
    float* rsA = Btp + Bc * NG * Nc * 4;        // [2880]
    float* rsB = rsA + Bc * Nc;                 // [2880]  (contiguous after rsA)
    int*   gsplit = (int*)(rsB + Bc * Nc);      // [1]

    fillw_kernel<<<dim3(32), 256, 0, stream>>>(W1, W2, b1, W1p, b1p, gsplit, rsA);
    proj_kernel<<<dim3(360, 5), 64, 0, stream>>>(emb, W1p, b1p, Avp, Btp, rsA, rsB);
    edge_kernel<<<dim3(90, 2, Bc), 256, 0, stream>>>(Avp, Btp, b2, rsA, rsB, gsplit, out);
}

// Round 11
// 50.622 us; speedup vs baseline: 1.0533x; 1.0533x over previous
//
#include <hip/hip_runtime.h>

#define Bc 8
#define Nc 360
#define Dc 128
#define NSLOT 132      // padded slots per side = 33 groups of 4
#define NG 33
#define NC2 264        // valid slots both sides (B-side first, then A-side)
#define NC2P 320       // padded to 5*64 for 5 cols/lane

typedef float f32x4 __attribute__((ext_vector_type(4)));

// ---------------- fillw: permutation + packed/permuted/0.5*w2-scaled W1 + b1p ----------------
// Wave 0 recomputes the sign permutation (positives of w2 first, zero-pad to group-of-4)
// into LDS; block fills its k4 slice of W1p (zero-padded cols NC2..NC2P). Block 0 writes gsplit.
__global__ __launch_bounds__(256) void fillw_kernel(
    const float* __restrict__ W1, const float* __restrict__ W2, const float* __restrict__ b1,
    float* __restrict__ W1p, float* __restrict__ b1p, int* __restrict__ gsplit_g)
{
    __shared__ int pmap_s[NSLOT];
    const int t  = threadIdx.x;
    const int k4 = blockIdx.x;                        // 0..31

    if (t < 64) {                                     // exactly wave 0
        const int lane = t;
        pmap_s[lane] = -1; pmap_s[64 + lane] = -1;
        if (lane < 4) pmap_s[128 + lane] = -1;
        const bool p0 = W2[lane] >= 0.0f;
        const bool p1 = W2[64 + lane] >= 0.0f;
        const unsigned long long m0 = __ballot(p0);
        const unsigned long long m1 = __ballot(p1);
        const unsigned long long below = (lane == 0) ? 0ull : (~0ull >> (64 - lane));
        const int cnt = __popcll(m0) + __popcll(m1);
        const int gs  = (cnt + 3) >> 2;
        if (lane == 0 && k4 == 0) *gsplit_g = gs;
        const int pr0 = __popcll(m0 & below);
        const int pr1 = __popcll(m0) + __popcll(m1 & below);
        const int nr0 = __popcll(~m0 & below);
        const int nr1 = __popcll(~m0) + __popcll(~m1 & below);
        // same-wave LDS writes are program-ordered: clears above, ranked scatter below
        if (p0) pmap_s[pr0] = lane;      else pmap_s[gs * 4 + nr0] = lane;
        if (p1) pmap_s[pr1] = 64 + lane; else pmap_s[gs * 4 + nr1] = 64 + lane;
    }
    __syncthreads();

    for (int c = t; c < NC2P; c += 256) {
        f32x4 v = {0.f, 0.f, 0.f, 0.f};
        float bv = 0.0f;
        if (c < NC2) {
            const int side = (c >= NSLOT);           // 0 = B (sender), 1 = A (receiver)
            const int cm   = side ? c - NSLOT : c;
            const int pd   = pmap_s[cm];
            if (pd >= 0) {
                const float sc = 0.5f * W2[pd];
                const float* src = W1 + pd * (2 * Dc) + side * Dc + k4 * 4;
                v[0] = sc * src[0]; v[1] = sc * src[1]; v[2] = sc * src[2]; v[3] = sc * src[3];
                if (side) bv = sc * b1[pd];
            }
        }
        *(f32x4*)(W1p + (k4 * NC2P + c) * 4) = v;
        if (k4 == 0) b1p[c] = bv;
    }
}

// ---------------- proj (edge-structure clone) ----------------
// Wave = 1 emb row x 320 slot-cols (5 per lane). emb row batch-preloaded to registers in
// 2 chunks of 64 floats (one wait per chunk); inner loop = pure {coalesced W1p b128 + FMA}.
// Wave owns the full row -> rsA/rsB via shfl reduce + direct store (no atomics, no zeroing).
__global__ __launch_bounds__(256) void proj_kernel(
    const float* __restrict__ emb, const float* __restrict__ W1p, const float* __restrict__ b1p,
    float* __restrict__ Avp, float* __restrict__ Btp,
    float* __restrict__ rsA, float* __restrict__ rsB)
{
    const int t    = threadIdx.x;
    const int lane = t & 63;
    const int wid  = __builtin_amdgcn_readfirstlane(t >> 6);
    const int row  = blockIdx.x * 4 + wid;           // 0..2879, uniform per wave

    float acc[5];
    #pragma unroll
    for (int q = 0; q < 5; ++q) acc[q] = b1p[q * 64 + lane];   // coalesced

    const float* ep    = emb + row * Dc;             // uniform
    const float* wbase = W1p + lane * 4;             // per-lane

    #pragma unroll
    for (int ch = 0; ch < 2; ++ch) {
        float e_ch[64];                              // batched uniform preload (one wait)
        #pragma unroll
        for (int s = 0; s < 16; ++s)
            *(f32x4*)&e_ch[s * 4] = *(const f32x4*)(ep + ch * 64 + s * 4);
        #pragma unroll
        for (int k4 = 0; k4 < 16; ++k4) {
            const int kk = ch * 16 + k4;
            f32x4 wv[5];
            #pragma unroll
            for (int q = 0; q < 5; ++q)
                wv[q] = *(const f32x4*)(wbase + (kk * NC2P + q * 64) * 4);  // coalesced b128
            #pragma unroll
            for (int e = 0; e < 4; ++e) {
                const float ev = e_ch[k4 * 4 + e];   // static index (reg-resident)
                #pragma unroll
                for (int q = 0; q < 5; ++q)
                    acc[q] = fmaf(wv[q][e], ev, acc[q]);
            }
        }
    }

    const int bidx = row / Nc;                       // uniform
    const int n    = row - bidx * Nc;

    float vA = 0.0f, vB = 0.0f;
    #pragma unroll
    for (int q = 0; q < 5; ++q) {
        const int c = q * 64 + lane;
        if (c < NC2) {
            const int side = (c >= NSLOT);
            const int cm   = side ? c - NSLOT : c;
            if (side) { Avp[(bidx * Nc + n) * NSLOT + cm] = acc[q];                      vA += acc[q]; }
            else      { Btp[((bidx * NG + (cm >> 2)) * Nc + n) * 4 + (cm & 3)] = acc[q]; vB += acc[q]; }
        }
    }
    #pragma unroll
    for (int m = 32; m >= 1; m >>= 1) { vA += __shfl_xor(vA, m); vB += __shfl_xor(vB, m); }
    if (lane == 0) { rsA[bidx * Nc + n] = vA; rsB[bidx * Nc + n] = vB; }
}

// ---------------- edge (unchanged — believed ~5 us) ----------------
// out[b,i,j] = relu( b2 + rsA[i] + rsB[j] + sum_g sgn_g * sum_e |a[g,e] + b[j,g,e]| )
__global__ __launch_bounds__(256) void edge_kernel(
    const float* __restrict__ Avp, const float* __restrict__ Btp,
    const float* __restrict__ b2, const float* __restrict__ rsA,
    const float* __restrict__ rsB, const int* __restrict__ gsplit_p,
    float* __restrict__ out)
{
    const int t    = threadIdx.x;
    const int lane = t & 63;
    const int wid  = __builtin_amdgcn_readfirstlane(t >> 6);
    const int b    = blockIdx.z;
    const int i    = blockIdx.x * 4 + wid;           // uniform per wave
    const int j0   = blockIdx.y * 168;               // halves [0,192) and [168,360): overlap idempotent
    const int gsplit = *gsplit_p;                    // uniform

    const float* arow = Avp + (b * Nc + i) * NSLOT;  // uniform -> s_load
    const float* bp   = Btp + (b * NG * Nc + j0 + lane) * 4;   // per-lane; + g*Nc*4 per group

    float acc0 = 0.0f, acc1 = 0.0f, acc2 = 0.0f;

    #pragma unroll
    for (int ch = 0; ch < 3; ++ch) {
        float a_ch[44];
        #pragma unroll
        for (int s = 0; s < 44; ++s) a_ch[s] = arow[ch * 44 + s];   // uniform, batched
        #pragma unroll
        for (int g2 = 0; g2 < 11; ++g2) {
            const int g = ch * 11 + g2;
            const float sg = (g < gsplit) ? 1.0f : -1.0f;            // uniform select
            const f32x4 b0 = *(const f32x4*)(bp + (g * Nc +   0) * 4);
            const f32x4 b1v = *(const f32x4*)(bp + (g * Nc +  64) * 4);
            const f32x4 b2v = *(const f32x4*)(bp + (g * Nc + 128) * 4);
            #pragma unroll
            for (int e = 0; e < 4; ++e) {
                const float a = a_ch[g2 * 4 + e];
                acc0 = fmaf(sg, fabsf(a + b0[e]),  acc0);
                acc1 = fmaf(sg, fabsf(a + b1v[e]), acc1);
                acc2 = fmaf(sg, fabsf(a + b2v[e]), acc2);
            }
        }
    }

    const float base = b2[0] + rsA[b * Nc + i];
    float* orow = out + (b * Nc + i) * Nc;
    orow[j0 + lane      ] = fmaxf(base + rsB[b * Nc + j0 + lane      ] + acc0, 0.0f);
    orow[j0 + lane +  64] = fmaxf(base + rsB[b * Nc + j0 + lane +  64] + acc1, 0.0f);
    orow[j0 + lane + 128] = fmaxf(base + rsB[b * Nc + j0 + lane + 128] + acc2, 0.0f);
}

extern "C" void kernel_launch(void* const* d_in, const int* in_sizes, int n_in,
                              void* d_out, int out_size, void* d_ws, size_t ws_size,
                              hipStream_t stream) {
    const float* emb = (const float*)d_in[0];   // [B,N,D]
    const float* W1  = (const float*)d_in[1];   // [D, 2D]
    const float* b1  = (const float*)d_in[2];   // [D]
    const float* W2  = (const float*)d_in[3];   // [1, D]
    const float* b2  = (const float*)d_in[4];   // [1]
    float* out = (float*)d_out;                 // [B,N,N,1]

    float* W1p = (float*)d_ws;                  // [32][320][4]          = 40960
    float* b1p = W1p + 32 * NC2P * 4;           // [320]
    float* Avp = b1p + NC2P;                    // [2880][132]           = 380160
    float* Btp = Avp + Bc * Nc * NSLOT;         // [8][33][360][4]       = 380160
    float* rsA = Btp + Bc * NG * Nc * 4;        // [2880]
    float* rsB = rsA + Bc * Nc;                 // [2880]
    int*   gsplit = (int*)(rsB + Bc * Nc);      // [1]

    fillw_kernel<<<dim3(32), 256, 0, stream>>>(W1, W2, b1, W1p, b1p, gsplit);
    proj_kernel<<<dim3(720), 256, 0, stream>>>(emb, W1p, b1p, Avp, Btp, rsA, rsB);
    edge_kernel<<<dim3(90, 2, Bc), 256, 0, stream>>>(Avp, Btp, b2, rsA, rsB, gsplit, out);
}